// Round 11
// baseline (264.057 us; speedup 1.0000x reference)
//
#include <hip/hip_runtime.h>
#include <hip/hip_bf16.h>
#include <stdint.h>

typedef __attribute__((ext_vector_type(4))) float f32x4;
typedef __attribute__((ext_vector_type(8))) __bf16 bf16x8;

#define AS1 __attribute__((address_space(1)))
#define AS3 __attribute__((address_space(3)))

#if __has_builtin(__builtin_amdgcn_exp2f)
#define EXP2(x) __builtin_amdgcn_exp2f(x)
#else
#define EXP2(x) exp2f(x)
#endif

__device__ __forceinline__ ushort f2bf(float f) {
  uint32_t u = __builtin_bit_cast(uint32_t, f);
  u += 0x7fffu + ((u >> 16) & 1u);
  return (ushort)(u >> 16);
}
__device__ __forceinline__ float bf2f(ushort h) {
  uint32_t u = ((uint32_t)h) << 16;
  return __builtin_bit_cast(float, u);
}

#define SCK 0.18033688011112042f

#define GLD(src, dst) \
  __builtin_amdgcn_global_load_lds((const AS1 uint32_t*)(src), (AS3 uint32_t*)(dst), 16, 0, 0)

#define BARRIER()                          \
  do {                                     \
    __builtin_amdgcn_sched_barrier(0);     \
    __builtin_amdgcn_s_barrier();          \
    __builtin_amdgcn_sched_barrier(0);     \
  } while (0)

// ---------------- prep: weight transposes (z=0..3) + x f32->bf16 (z=4) ----------------

__global__ void k_prep(const float* __restrict__ x, const float* __restrict__ Wq,
                       const float* __restrict__ Wk, const float* __restrict__ Wv,
                       const float* __restrict__ Wo, ushort* __restrict__ xb,
                       ushort* __restrict__ Wt, ushort* __restrict__ Wot) {
  __shared__ float tile[32][33];
  int z = blockIdx.z;
  int tx = threadIdx.x, ty = threadIdx.y;  // (32,8)
  if (z == 4) {
    int base = (blockIdx.y * 32 + blockIdx.x) * 256 + ty * 32 + tx;
#pragma unroll
    for (int i = 0; i < 4; i++) {
      int idx = base + i * 262144;
      float4 v = ((const float4*)x)[idx];
      ushort4 o;
      o.x = f2bf(v.x); o.y = f2bf(v.y); o.z = f2bf(v.z); o.w = f2bf(v.w);
      ((ushort4*)xb)[idx] = o;
    }
    return;
  }
  const float* src = (z == 0) ? Wq : (z == 1) ? Wk : (z == 2) ? Wv : Wo;
  ushort* dst = (z < 3) ? (Wt + (size_t)z * 1048576) : Wot;
  float scale = (z == 1) ? SCK : 1.0f;
  int k0 = blockIdx.y * 32, n0 = blockIdx.x * 32;
#pragma unroll
  for (int i = 0; i < 4; i++)
    tile[ty + i * 8][tx] = src[(size_t)(k0 + ty + i * 8) * 1024 + n0 + tx];
  __syncthreads();
#pragma unroll
  for (int i = 0; i < 4; i++)
    dst[(size_t)(n0 + ty + i * 8) * 1024 + k0 + tx] = f2bf(tile[tx][ty + i * 8] * scale);
}

// ---------------- 128x128 BK=64 single-buffer GEMM, 3 blocks/CU (QKV) ----------------
__global__ __launch_bounds__(256, 3) void k_gemm_qkv(const ushort* __restrict__ A,
                                                     const ushort* __restrict__ Bt,
                                                     ushort* __restrict__ C,
                                                     const float* __restrict__ b0,
                                                     const float* __restrict__ b1,
                                                     const float* __restrict__ b2) {
  __shared__ ushort As[128 * 64];
  __shared__ ushort Bs[128 * 64];
  const int K = 1024, ldc = 3072;
  const int tid = threadIdx.x;
  const int lane = tid & 63;
  const int wid = tid >> 6;
  const int wr = wid >> 1, wc = wid & 1;
  const int l15 = lane & 15, l4 = lane >> 4;

  const int chunk = (int)gridDim.x >> 3;
  const int L = blockIdx.x;
  const int f = (L & 7) * chunk + (L >> 3);
  const int row0 = (f & 31) * 128;
  const int col0 = (f >> 5) * 128;
  const int T = K >> 6;

  const int rt = tid >> 3;
  const int cswz = ((tid & 7) ^ (rt & 7)) * 8;
  const ushort* Ap = A + (size_t)(row0 + rt) * K + cswz;
  const ushort* Bp = Bt + (size_t)(col0 + rt) * K + cswz;

  int aoff[4][2], boff[4][2];
#pragma unroll
  for (int m = 0; m < 4; m++) {
    int r = wr * 64 + m * 16 + l15;
#pragma unroll
    for (int ks = 0; ks < 2; ks++)
      aoff[m][ks] = r * 128 + (((ks * 4 + l4) ^ (r & 7)) << 4);
  }
#pragma unroll
  for (int n = 0; n < 4; n++) {
    int r = wc * 64 + n * 16 + l15;
#pragma unroll
    for (int ks = 0; ks < 2; ks++)
      boff[n][ks] = r * 128 + (((ks * 4 + l4) ^ (r & 7)) << 4);
  }

  f32x4 acc[4][4] = {};

  for (int t = 0; t < T; ++t) {
#pragma unroll
    for (int i = 0; i < 4; i++)
      GLD(Ap + (size_t)(32 * i) * K + t * 64, (char*)As + (i * 256 + tid) * 16);
#pragma unroll
    for (int i = 0; i < 4; i++)
      GLD(Bp + (size_t)(32 * i) * K + t * 64, (char*)Bs + (i * 256 + tid) * 16);
    asm volatile("s_waitcnt vmcnt(0)" ::: "memory");
    BARRIER();

    bf16x8 af[4][2], bf_[4][2];
#pragma unroll
    for (int m = 0; m < 4; m++)
#pragma unroll
      for (int ks = 0; ks < 2; ks++)
        af[m][ks] = *(const bf16x8*)((const char*)As + aoff[m][ks]);
#pragma unroll
    for (int n = 0; n < 4; n++)
#pragma unroll
      for (int ks = 0; ks < 2; ks++)
        bf_[n][ks] = *(const bf16x8*)((const char*)Bs + boff[n][ks]);

    __builtin_amdgcn_s_setprio(1);
#pragma unroll
    for (int m = 0; m < 4; m++)
#pragma unroll
      for (int n = 0; n < 4; n++)
#pragma unroll
        for (int ks = 0; ks < 2; ks++)
          acc[m][n] = __builtin_amdgcn_mfma_f32_16x16x32_bf16(af[m][ks], bf_[n][ks],
                                                              acc[m][n], 0, 0, 0);
    __builtin_amdgcn_s_setprio(0);
    BARRIER();
  }

#pragma unroll
  for (int m = 0; m < 4; m++)
#pragma unroll
    for (int n = 0; n < 4; n++) {
      int colg = col0 + wc * 64 + n * 16 + l15;
      float bias = (colg < 1024) ? b0[colg]
                                 : ((colg < 2048) ? b1[colg - 1024] * SCK : b2[colg - 2048]);
#pragma unroll
      for (int j = 0; j < 4; j++) {
        int rowg = row0 + wr * 64 + m * 16 + l4 * 4 + j;
        C[(size_t)rowg * ldc + colg] = f2bf(acc[m][n][j] + bias);
      }
    }
}

// ---------------- attention pass 1: Z[tk] = sum_tq exp2(S) ----------------
// 48 KB LDS (3 blocks/CU): static K tile (32 KB) staged into ring[0..1], read
// into registers, then the whole 48 KB becomes the 3-buffer Q ring (tile t ->
// ring[(t+2)%3]; Q0 pre-staged into ring[2] alongside K).
__global__ __launch_bounds__(256, 3) void k_attn_z(const ushort* __restrict__ QKV,
                                                   float* __restrict__ Zpart) {
  const int bid = blockIdx.x;
  const int xcd = bid & 7, kk = bid >> 3;
  const int g = xcd * 8 + (kk >> 3);     // group 0..63 = (s,bh)
  const int tkb = kk & 7;
  const int bh = g & 31, s = g >> 5;
  const int b = bh >> 4, h = bh & 15;
  const int tid = threadIdx.x, lane = tid & 63, w = tid >> 6;
  const int l15 = lane & 15, l4 = lane >> 4;
  const size_t rs = 3072;

  __shared__ ushort ring[3][128 * 64];  // 48 KB total

  const ushort* Kbase = QKV + (size_t)(b * 2048 + tkb * 256) * rs + 1024 + h * 64;
  const ushort* Qbase = QKV + (size_t)(b * 2048 + s * 1024) * rs + h * 64;
  const int csl = ((tid & 7) ^ ((tid >> 3) & 7)) * 8;

  // stage K (32 KB -> ring[0..1]) and Q0 (-> ring[2])
#pragma unroll
  for (int i = 0; i < 8; i++) {
    int c = i * 256 + tid;
    GLD(Kbase + (size_t)(c >> 3) * rs + csl, (char*)ring[0] + c * 16);
  }
  const ushort* gq[4];
#pragma unroll
  for (int i = 0; i < 4; i++) {
    int c = i * 256 + tid;
    gq[i] = Qbase + (size_t)(c >> 3) * rs + csl;
    GLD(gq[i], (char*)ring[2] + c * 16);
  }
  asm volatile("s_waitcnt vmcnt(0)" ::: "memory");
  BARRIER();

  bf16x8 kf[4][2];
#pragma unroll
  for (int m = 0; m < 4; m++)
#pragma unroll
    for (int d = 0; d < 2; d++) {
      int r = w * 64 + m * 16 + l15;
      kf[m][d] =
          *(const bf16x8*)((const char*)ring[0] + r * 128 + (((d * 4 + l4) ^ (r & 7)) << 4));
    }
  asm volatile("s_waitcnt lgkmcnt(0)" ::: "memory");
  __builtin_amdgcn_sched_barrier(0);
  BARRIER();  // all waves hold K in regs; ring[0..1] now free

  // stage Q1 -> ring[0]
#pragma unroll
  for (int i = 0; i < 4; i++) {
    int c = i * 256 + tid;
    GLD(gq[i] + 128 * rs, (char*)ring[0] + c * 16);
  }

  float z[4][4] = {};
  const f32x4 zero4 = {0.f, 0.f, 0.f, 0.f};

  for (int t = 0; t < 8; ++t) {
    if (t + 2 < 8) {
      char* qd = (char*)ring[(t + 4) % 3];
#pragma unroll
      for (int i = 0; i < 4; i++) {
        int c = i * 256 + tid;
        GLD(gq[i] + (size_t)(t + 2) * 128 * rs, qd + c * 16);
      }
    }
    const char* qb = (const char*)ring[(t + 2) % 3];
    f32x4 acc[4][8];
    __builtin_amdgcn_s_setprio(1);
#pragma unroll
    for (int d = 0; d < 2; d++)
#pragma unroll
      for (int n = 0; n < 8; n++) {
        int r = n * 16 + l15;
        bf16x8 qf = *(const bf16x8*)(qb + r * 128 + (((d * 4 + l4) ^ (r & 7)) << 4));
#pragma unroll
        for (int m = 0; m < 4; m++)
          acc[m][n] = __builtin_amdgcn_mfma_f32_16x16x32_bf16(
              kf[m][d], qf, d == 0 ? zero4 : acc[m][n], 0, 0, 0);
      }
    __builtin_amdgcn_s_setprio(0);
#pragma unroll
    for (int m = 0; m < 4; m++)
#pragma unroll
      for (int n = 0; n < 8; n++)
#pragma unroll
        for (int j = 0; j < 4; j++) z[m][j] += EXP2(acc[m][n][j]);
    if (t < 6) {
      asm volatile("s_waitcnt vmcnt(4)" ::: "memory");
      BARRIER();
    } else if (t == 6) {
      asm volatile("s_waitcnt vmcnt(0)" ::: "memory");
      BARRIER();
    }
  }

#pragma unroll
  for (int m = 0; m < 4; m++)
#pragma unroll
    for (int j = 0; j < 4; j++) {
      float v = z[m][j];
      v += __shfl_xor(v, 1, 64);
      v += __shfl_xor(v, 2, 64);
      v += __shfl_xor(v, 4, 64);
      v += __shfl_xor(v, 8, 64);
      if (l15 == 0)
        Zpart[(size_t)s * 65536 + bh * 2048 + tkb * 256 + w * 64 + m * 16 + l4 * 4 + j] = v;
    }
}

// ---------------- attention pass 2: colsum[tq] = sum_tk exp2(S)/Z[tk] ----
__global__ __launch_bounds__(256, 3) void k_attn_cs(const ushort* __restrict__ QKV,
                                                    const float* __restrict__ Zpart,
                                                    float* __restrict__ csPart) {
  const int bid = blockIdx.x;
  const int xcd = bid & 7, kk = bid >> 3;
  const int g = xcd * 8 + (kk >> 3);
  const int tqb = kk & 7;
  const int bh = g & 31, s = g >> 5;
  const int b = bh >> 4, h = bh & 15;
  const int tid = threadIdx.x, lane = tid & 63, w = tid >> 6;
  const int l15 = lane & 15, l4 = lane >> 4;
  const size_t rs = 3072;

  __shared__ ushort ring[3][128 * 64];  // 48 KB total

  const ushort* Qbase = QKV + (size_t)(b * 2048 + tqb * 256) * rs + h * 64;
  const ushort* Kbase = QKV + (size_t)(b * 2048 + s * 1024) * rs + 1024 + h * 64;
  const float* zp = Zpart + bh * 2048 + s * 1024;
  const int csl = ((tid & 7) ^ ((tid >> 3) & 7)) * 8;

#pragma unroll
  for (int i = 0; i < 8; i++) {
    int c = i * 256 + tid;
    GLD(Qbase + (size_t)(c >> 3) * rs + csl, (char*)ring[0] + c * 16);
  }
  const ushort* gk[4];
#pragma unroll
  for (int i = 0; i < 4; i++) {
    int c = i * 256 + tid;
    gk[i] = Kbase + (size_t)(c >> 3) * rs + csl;
    GLD(gk[i], (char*)ring[2] + c * 16);
  }
  asm volatile("s_waitcnt vmcnt(0)" ::: "memory");
  BARRIER();

  bf16x8 qf[4][2];
#pragma unroll
  for (int m = 0; m < 4; m++)
#pragma unroll
    for (int d = 0; d < 2; d++) {
      int r = w * 64 + m * 16 + l15;
      qf[m][d] =
          *(const bf16x8*)((const char*)ring[0] + r * 128 + (((d * 4 + l4) ^ (r & 7)) << 4));
    }
  asm volatile("s_waitcnt lgkmcnt(0)" ::: "memory");
  __builtin_amdgcn_sched_barrier(0);
  BARRIER();  // Q in regs; ring[0..1] free

#pragma unroll
  for (int i = 0; i < 4; i++) {
    int c = i * 256 + tid;
    GLD(gk[i] + 128 * rs, (char*)ring[0] + c * 16);
  }

  float cs[4][4] = {};
  const f32x4 zero4 = {0.f, 0.f, 0.f, 0.f};

  for (int t = 0; t < 8; ++t) {
    // rz loads first (their wait leaves the K prefetch in flight)
    float rz[8];
#pragma unroll
    for (int n = 0; n < 8; n++) {
      int idx = t * 128 + n * 16 + l15;
      rz[n] = 1.0f / (zp[idx] + zp[65536 + idx]);
    }
    if (t + 2 < 8) {
      char* kd = (char*)ring[(t + 4) % 3];
#pragma unroll
      for (int i = 0; i < 4; i++) {
        int c = i * 256 + tid;
        GLD(gk[i] + (size_t)(t + 2) * 128 * rs, kd + c * 16);
      }
    }
    const char* kb = (const char*)ring[(t + 2) % 3];
    f32x4 acc[4][8];
    __builtin_amdgcn_s_setprio(1);
#pragma unroll
    for (int d = 0; d < 2; d++)
#pragma unroll
      for (int n = 0; n < 8; n++) {
        int r = n * 16 + l15;
        bf16x8 kft = *(const bf16x8*)(kb + r * 128 + (((d * 4 + l4) ^ (r & 7)) << 4));
#pragma unroll
        for (int m = 0; m < 4; m++)
          acc[m][n] = __builtin_amdgcn_mfma_f32_16x16x32_bf16(
              qf[m][d], kft, d == 0 ? zero4 : acc[m][n], 0, 0, 0);
      }
    __builtin_amdgcn_s_setprio(0);
#pragma unroll
    for (int m = 0; m < 4; m++)
#pragma unroll
      for (int n = 0; n < 8; n++)
#pragma unroll
        for (int j = 0; j < 4; j++)
          cs[m][j] = fmaf(EXP2(acc[m][n][j]), rz[n], cs[m][j]);
    if (t < 6) {
      asm volatile("s_waitcnt vmcnt(4)" ::: "memory");
      BARRIER();
    } else if (t == 6) {
      asm volatile("s_waitcnt vmcnt(0)" ::: "memory");
      BARRIER();
    }
  }

#pragma unroll
  for (int m = 0; m < 4; m++)
#pragma unroll
    for (int j = 0; j < 4; j++) {
      float v = cs[m][j];
      v += __shfl_xor(v, 1, 64);
      v += __shfl_xor(v, 2, 64);
      v += __shfl_xor(v, 4, 64);
      v += __shfl_xor(v, 8, 64);
      if (l15 == 0)
        csPart[(size_t)s * 65536 + bh * 2048 + tqb * 256 + w * 64 + m * 16 + l4 * 4 + j] = v;
    }
}

// ---------------- output GEMM: out = (V .* colsum) @ Wot + bo, fused ----------------
__global__ __launch_bounds__(256, 2) void k_gemm_out(const ushort* __restrict__ QKV,
                                                     const float* __restrict__ csPart,
                                                     const ushort* __restrict__ Wot,
                                                     float* __restrict__ out,
                                                     const float* __restrict__ bo) {
  __shared__ ushort As[2][128 * 64];  // 32 KB
  __shared__ ushort Bs[2][64 * 64];   // 16 KB
  const int tid = threadIdx.x;
  const int lane = tid & 63;
  const int wid = tid >> 6;
  const int wr = wid >> 1, wc = wid & 1;
  const int l15 = lane & 15, l4 = lane >> 4;

  const int L = blockIdx.x;
  const int f = (L & 7) * 64 + (L >> 3);
  const int row0 = (f & 31) * 128;
  const int col0 = (f >> 5) * 64;

  const int rt = tid >> 3, sl = tid & 7;
  int grow[4], gbh[4];
#pragma unroll
  for (int i = 0; i < 4; i++) {
    grow[i] = row0 + 32 * i + rt;
    gbh[i] = ((grow[i] >> 11) << 4) * 2048 + (grow[i] & 2047);  // b*16*2048 + tq
  }

  uint4 av[4];
  float csv[4];

#define ISSUE(t)                                                                   \
  do {                                                                             \
    _Pragma("unroll") for (int i = 0; i < 2; i++) {                                \
      int c = i * 256 + tid;                                                       \
      int rb = c >> 3;                                                             \
      GLD(Wot + (size_t)(col0 + rb) * 1024 + (t) * 64 + (((c & 7) ^ (rb & 7)) * 8),\
          (char*)Bs[(t) & 1] + c * 16);                                            \
    }                                                                              \
    _Pragma("unroll") for (int i = 0; i < 4; i++)                                  \
        av[i] = *(const uint4*)(QKV + (size_t)grow[i] * 3072 + 2048 + (t) * 64 +   \
                                sl * 8);                                           \
    _Pragma("unroll") for (int i = 0; i < 4; i++) {                                \
      int gg = gbh[i] + (t) * 2048;                                                \
      csv[i] = csPart[gg] + csPart[65536 + gg];                                    \
    }                                                                              \
  } while (0)

#define WRITE_A(t)                                                                 \
  do {                                                                             \
    _Pragma("unroll") for (int i = 0; i < 4; i++) {                                \
      int r = 32 * i + rt;                                                         \
      const ushort* pv = (const ushort*)&av[i];                                    \
      ushort o[8];                                                                 \
      _Pragma("unroll") for (int k = 0; k < 8; k++)                                \
          o[k] = f2bf(bf2f(pv[k]) * csv[i]);                                       \
      *(uint4*)((char*)As[(t) & 1] + r * 128 + ((sl ^ (r & 7)) << 4)) =            \
          *(const uint4*)o;                                                        \
    }                                                                              \
  } while (0)

  int aoff[4][2], boff[2][2];
#pragma unroll
  for (int m = 0; m < 4; m++) {
    int r = wr * 64 + m * 16 + l15;
#pragma unroll
    for (int ks = 0; ks < 2; ks++)
      aoff[m][ks] = r * 128 + (((ks * 4 + l4) ^ (r & 7)) << 4);
  }
#pragma unroll
  for (int n = 0; n < 2; n++) {
    int r = wc * 32 + n * 16 + l15;
#pragma unroll
    for (int ks = 0; ks < 2; ks++)
      boff[n][ks] = r * 128 + (((ks * 4 + l4) ^ (r & 7)) << 4);
  }

  f32x4 acc[4][2] = {};

  ISSUE(0);
  asm volatile("s_waitcnt vmcnt(0)" ::: "memory");
  WRITE_A(0);
  asm volatile("s_waitcnt lgkmcnt(0)" ::: "memory");
  BARRIER();

  for (int t = 0; t < 16; ++t) {
    if (t < 15) ISSUE(t + 1);
    __builtin_amdgcn_sched_barrier(0);
    const char* Ab = (const char*)As[t & 1];
    const char* Bb = (const char*)Bs[t & 1];
    bf16x8 af[4][2], bf_[2][2];
#pragma unroll
    for (int m = 0; m < 4; m++)
#pragma unroll
      for (int ks = 0; ks < 2; ks++)
        af[m][ks] = *(const bf16x8*)(Ab + aoff[m][ks]);
#pragma unroll
    for (int n = 0; n < 2; n++)
#pragma unroll
      for (int ks = 0; ks < 2; ks++)
        bf_[n][ks] = *(const bf16x8*)(Bb + boff[n][ks]);
    __builtin_amdgcn_s_setprio(1);
#pragma unroll
    for (int m = 0; m < 4; m++)
#pragma unroll
      for (int n = 0; n < 2; n++)
#pragma unroll
        for (int ks = 0; ks < 2; ks++)
          acc[m][n] = __builtin_amdgcn_mfma_f32_16x16x32_bf16(af[m][ks], bf_[n][ks],
                                                              acc[m][n], 0, 0, 0);
    __builtin_amdgcn_s_setprio(0);
    if (t < 15) {
      asm volatile("s_waitcnt vmcnt(0)" ::: "memory");
      WRITE_A(t + 1);
      asm volatile("s_waitcnt lgkmcnt(0)" ::: "memory");
    }
    BARRIER();
  }

#undef ISSUE
#undef WRITE_A

#pragma unroll
  for (int m = 0; m < 4; m++)
#pragma unroll
    for (int n = 0; n < 2; n++) {
      int colg = col0 + wc * 32 + n * 16 + l15;
      float bias = bo[colg];
#pragma unroll
      for (int j = 0; j < 4; j++) {
        int rowg = row0 + wr * 64 + m * 16 + l4 * 4 + j;
        out[(size_t)rowg * 1024 + colg] = acc[m][n][j] + bias;
      }
    }
}

// ---------------- launch ----------------

extern "C" void kernel_launch(void* const* d_in, const int* in_sizes, int n_in,
                              void* d_out, int out_size, void* d_ws, size_t ws_size,
                              hipStream_t stream) {
  const float* x = (const float*)d_in[0];
  const float* Wq = (const float*)d_in[1];
  const float* bq = (const float*)d_in[2];
  const float* Wk = (const float*)d_in[3];
  const float* bk = (const float*)d_in[4];
  const float* Wv = (const float*)d_in[5];
  const float* bv = (const float*)d_in[6];
  const float* Wo = (const float*)d_in[7];
  const float* bo = (const float*)d_in[8];

  char* ws = (char*)d_ws;
  ushort* xb     = (ushort*)(ws);                  // 4096x1024 bf16   (8 MB)
  ushort* Wt     = (ushort*)(ws + 8388608);        // 3072x1024 bf16   (6 MB)
  ushort* Wot    = (ushort*)(ws + 14680064);       // 1024x1024 bf16   (2 MB)
  ushort* QKV    = (ushort*)(ws + 16777216);       // 4096x3072 bf16   (24 MB)
  float* Zpart   = (float*)(ws + 41943040);        // 2x32x2048 f32    (512 KB)
  float* csPart  = (float*)(ws + 42467328);        // 2x32x2048 f32    (512 KB)

  k_prep<<<dim3(32, 32, 5), dim3(32, 8), 0, stream>>>(x, Wq, Wk, Wv, Wo, xb, Wt, Wot);
  k_gemm_qkv<<<768, 256, 0, stream>>>(xb, Wt, QKV, bq, bk, bv);
  k_attn_z<<<512, 256, 0, stream>>>(QKV, Zpart);
  k_attn_cs<<<512, 256, 0, stream>>>(QKV, Zpart, csPart);
  k_gemm_out<<<512, 256, 0, stream>>>(QKV, csPart, Wot, (float*)d_out, bo);
}

// Round 12
// 218.645 us; speedup vs baseline: 1.2077x; 1.2077x over previous
//
#include <hip/hip_runtime.h>
#include <hip/hip_bf16.h>
#include <stdint.h>

typedef __attribute__((ext_vector_type(4))) float f32x4;
typedef __attribute__((ext_vector_type(8))) __bf16 bf16x8;

#define AS1 __attribute__((address_space(1)))
#define AS3 __attribute__((address_space(3)))

#if __has_builtin(__builtin_amdgcn_exp2f)
#define EXP2(x) __builtin_amdgcn_exp2f(x)
#else
#define EXP2(x) exp2f(x)
#endif

__device__ __forceinline__ ushort f2bf(float f) {
  uint32_t u = __builtin_bit_cast(uint32_t, f);
  u += 0x7fffu + ((u >> 16) & 1u);
  return (ushort)(u >> 16);
}
__device__ __forceinline__ float bf2f(ushort h) {
  uint32_t u = ((uint32_t)h) << 16;
  return __builtin_bit_cast(float, u);
}

#define SCK 0.18033688011112042f

#define GLD(src, dst) \
  __builtin_amdgcn_global_load_lds((const AS1 uint32_t*)(src), (AS3 uint32_t*)(dst), 16, 0, 0)

#define BARRIER()                          \
  do {                                     \
    __builtin_amdgcn_sched_barrier(0);     \
    __builtin_amdgcn_s_barrier();          \
    __builtin_amdgcn_sched_barrier(0);     \
  } while (0)

// ---------------- prep: weight transposes (z=0..3) + x f32->bf16 (z=4) ----------------

__global__ void k_prep(const float* __restrict__ x, const float* __restrict__ Wq,
                       const float* __restrict__ Wk, const float* __restrict__ Wv,
                       const float* __restrict__ Wo, ushort* __restrict__ xb,
                       ushort* __restrict__ Wt, ushort* __restrict__ Wot) {
  __shared__ float tile[32][33];
  int z = blockIdx.z;
  int tx = threadIdx.x, ty = threadIdx.y;  // (32,8)
  if (z == 4) {
    int base = (blockIdx.y * 32 + blockIdx.x) * 256 + ty * 32 + tx;
#pragma unroll
    for (int i = 0; i < 4; i++) {
      int idx = base + i * 262144;
      float4 v = ((const float4*)x)[idx];
      ushort4 o;
      o.x = f2bf(v.x); o.y = f2bf(v.y); o.z = f2bf(v.z); o.w = f2bf(v.w);
      ((ushort4*)xb)[idx] = o;
    }
    return;
  }
  const float* src = (z == 0) ? Wq : (z == 1) ? Wk : (z == 2) ? Wv : Wo;
  ushort* dst = (z < 3) ? (Wt + (size_t)z * 1048576) : Wot;
  float scale = (z == 1) ? SCK : 1.0f;
  int k0 = blockIdx.y * 32, n0 = blockIdx.x * 32;
#pragma unroll
  for (int i = 0; i < 4; i++)
    tile[ty + i * 8][tx] = src[(size_t)(k0 + ty + i * 8) * 1024 + n0 + tx];
  __syncthreads();
#pragma unroll
  for (int i = 0; i < 4; i++)
    dst[(size_t)(n0 + ty + i * 8) * 1024 + k0 + tx] = f2bf(tile[tx][ty + i * 8] * scale);
}

// ---------------- 128x128 BK=64 single-buffer GEMM, 3 blocks/CU (QKV) ----------------
__global__ __launch_bounds__(256, 3) void k_gemm_qkv(const ushort* __restrict__ A,
                                                     const ushort* __restrict__ Bt,
                                                     ushort* __restrict__ C,
                                                     const float* __restrict__ b0,
                                                     const float* __restrict__ b1,
                                                     const float* __restrict__ b2) {
  __shared__ ushort As[128 * 64];
  __shared__ ushort Bs[128 * 64];
  const int K = 1024, ldc = 3072;
  const int tid = threadIdx.x;
  const int lane = tid & 63;
  const int wid = tid >> 6;
  const int wr = wid >> 1, wc = wid & 1;
  const int l15 = lane & 15, l4 = lane >> 4;

  const int chunk = (int)gridDim.x >> 3;
  const int L = blockIdx.x;
  const int f = (L & 7) * chunk + (L >> 3);
  const int row0 = (f & 31) * 128;
  const int col0 = (f >> 5) * 128;
  const int T = K >> 6;

  const int rt = tid >> 3;
  const int cswz = ((tid & 7) ^ (rt & 7)) * 8;
  const ushort* Ap = A + (size_t)(row0 + rt) * K + cswz;
  const ushort* Bp = Bt + (size_t)(col0 + rt) * K + cswz;

  int aoff[4][2], boff[4][2];
#pragma unroll
  for (int m = 0; m < 4; m++) {
    int r = wr * 64 + m * 16 + l15;
#pragma unroll
    for (int ks = 0; ks < 2; ks++)
      aoff[m][ks] = r * 128 + (((ks * 4 + l4) ^ (r & 7)) << 4);
  }
#pragma unroll
  for (int n = 0; n < 4; n++) {
    int r = wc * 64 + n * 16 + l15;
#pragma unroll
    for (int ks = 0; ks < 2; ks++)
      boff[n][ks] = r * 128 + (((ks * 4 + l4) ^ (r & 7)) << 4);
  }

  f32x4 acc[4][4] = {};

  for (int t = 0; t < T; ++t) {
#pragma unroll
    for (int i = 0; i < 4; i++)
      GLD(Ap + (size_t)(32 * i) * K + t * 64, (char*)As + (i * 256 + tid) * 16);
#pragma unroll
    for (int i = 0; i < 4; i++)
      GLD(Bp + (size_t)(32 * i) * K + t * 64, (char*)Bs + (i * 256 + tid) * 16);
    asm volatile("s_waitcnt vmcnt(0)" ::: "memory");
    BARRIER();

    bf16x8 af[4][2], bf_[4][2];
#pragma unroll
    for (int m = 0; m < 4; m++)
#pragma unroll
      for (int ks = 0; ks < 2; ks++)
        af[m][ks] = *(const bf16x8*)((const char*)As + aoff[m][ks]);
#pragma unroll
    for (int n = 0; n < 4; n++)
#pragma unroll
      for (int ks = 0; ks < 2; ks++)
        bf_[n][ks] = *(const bf16x8*)((const char*)Bs + boff[n][ks]);

    __builtin_amdgcn_s_setprio(1);
#pragma unroll
    for (int m = 0; m < 4; m++)
#pragma unroll
      for (int n = 0; n < 4; n++)
#pragma unroll
        for (int ks = 0; ks < 2; ks++)
          acc[m][n] = __builtin_amdgcn_mfma_f32_16x16x32_bf16(af[m][ks], bf_[n][ks],
                                                              acc[m][n], 0, 0, 0);
    __builtin_amdgcn_s_setprio(0);
    BARRIER();
  }

#pragma unroll
  for (int m = 0; m < 4; m++)
#pragma unroll
    for (int n = 0; n < 4; n++) {
      int colg = col0 + wc * 64 + n * 16 + l15;
      float bias = (colg < 1024) ? b0[colg]
                                 : ((colg < 2048) ? b1[colg - 1024] * SCK : b2[colg - 2048]);
#pragma unroll
      for (int j = 0; j < 4; j++) {
        int rowg = row0 + wr * 64 + m * 16 + l4 * 4 + j;
        C[(size_t)rowg * ldc + colg] = f2bf(acc[m][n][j] + bias);
      }
    }
}

// ---------------- attention pass 1: Z[tk] partials ----------------
// Block (s,bh,tkb): static K tile 256 rows (ring[0..1] -> regs), streams Q rows
// s*512..+512 (4 tiles, 3-slot ring, counted vmcnt). n-chunked acc (2x acc[4][4])
// keeps total regs ~150 -> 3 blocks/CU at 48 KB LDS. Grid 1024, XCD by bh.
__global__ __launch_bounds__(256, 2) void k_attn_z(const ushort* __restrict__ QKV,
                                                   float* __restrict__ Zpart) {
  const int bid = blockIdx.x;
  const int xcd = bid & 7, local = bid >> 3;      // local 0..127
  const int bh = xcd * 4 + (local >> 5);
  const int s = (local >> 3) & 3;
  const int tkb = local & 7;
  const int b = bh >> 4, h = bh & 15;
  const int tid = threadIdx.x, lane = tid & 63, w = tid >> 6;
  const int l15 = lane & 15, l4 = lane >> 4;
  const size_t rs = 3072;

  __shared__ ushort ring[3][128 * 64];  // 48 KB

  const ushort* Kbase = QKV + (size_t)(b * 2048 + tkb * 256) * rs + 1024 + h * 64;
  const ushort* Qbase = QKV + (size_t)(b * 2048 + s * 512) * rs + h * 64;
  const int csl = ((tid & 7) ^ ((tid >> 3) & 7)) * 8;

#pragma unroll
  for (int i = 0; i < 8; i++) {
    int c = i * 256 + tid;
    GLD(Kbase + (size_t)(c >> 3) * rs + csl, (char*)ring[0] + c * 16);
  }
  const ushort* gq[4];
#pragma unroll
  for (int i = 0; i < 4; i++) {
    int c = i * 256 + tid;
    gq[i] = Qbase + (size_t)(c >> 3) * rs + csl;
    GLD(gq[i], (char*)ring[2] + c * 16);
  }
  asm volatile("s_waitcnt vmcnt(0)" ::: "memory");
  BARRIER();

  bf16x8 kf[4][2];
#pragma unroll
  for (int m = 0; m < 4; m++)
#pragma unroll
    for (int d = 0; d < 2; d++) {
      int r = w * 64 + m * 16 + l15;
      kf[m][d] =
          *(const bf16x8*)((const char*)ring[0] + r * 128 + (((d * 4 + l4) ^ (r & 7)) << 4));
    }
  asm volatile("s_waitcnt lgkmcnt(0)" ::: "memory");
  __builtin_amdgcn_sched_barrier(0);
  BARRIER();  // K in regs; ring[0..1] free

#pragma unroll
  for (int i = 0; i < 4; i++) {
    int c = i * 256 + tid;
    GLD(gq[i] + 128 * rs, (char*)ring[0] + c * 16);  // Q1
  }

  float z[4][4] = {};
  const f32x4 zero4 = {0.f, 0.f, 0.f, 0.f};

  for (int t = 0; t < 4; ++t) {
    if (t < 2) {
      char* qd = (char*)ring[(t + 4) % 3];
#pragma unroll
      for (int i = 0; i < 4; i++) {
        int c = i * 256 + tid;
        GLD(gq[i] + (size_t)(t + 2) * 128 * rs, qd + c * 16);
      }
    }
    const char* qb = (const char*)ring[(t + 2) % 3];
#pragma unroll
    for (int half = 0; half < 2; ++half) {
      f32x4 acc[4][4];
      __builtin_amdgcn_s_setprio(1);
#pragma unroll
      for (int d = 0; d < 2; d++)
#pragma unroll
        for (int nn = 0; nn < 4; nn++) {
          int r = (half * 4 + nn) * 16 + l15;
          bf16x8 qf = *(const bf16x8*)(qb + r * 128 + (((d * 4 + l4) ^ (r & 7)) << 4));
#pragma unroll
          for (int m = 0; m < 4; m++)
            acc[m][nn] = __builtin_amdgcn_mfma_f32_16x16x32_bf16(
                kf[m][d], qf, d == 0 ? zero4 : acc[m][nn], 0, 0, 0);
        }
      __builtin_amdgcn_s_setprio(0);
#pragma unroll
      for (int m = 0; m < 4; m++)
#pragma unroll
        for (int nn = 0; nn < 4; nn++)
#pragma unroll
          for (int j = 0; j < 4; j++) z[m][j] += EXP2(acc[m][nn][j]);
    }
    if (t < 2) {
      asm volatile("s_waitcnt vmcnt(4)" ::: "memory");
      BARRIER();
    } else if (t == 2) {
      asm volatile("s_waitcnt vmcnt(0)" ::: "memory");
      BARRIER();
    }
  }

#pragma unroll
  for (int m = 0; m < 4; m++)
#pragma unroll
    for (int j = 0; j < 4; j++) {
      float v = z[m][j];
      v += __shfl_xor(v, 1, 64);
      v += __shfl_xor(v, 2, 64);
      v += __shfl_xor(v, 4, 64);
      v += __shfl_xor(v, 8, 64);
      if (l15 == 0)
        Zpart[(size_t)s * 65536 + bh * 2048 + tkb * 256 + w * 64 + m * 16 + l4 * 4 + j] = v;
    }
}

// ---------------- attention pass 2: colsum partials ----------------
__global__ __launch_bounds__(256, 2) void k_attn_cs(const ushort* __restrict__ QKV,
                                                    const float* __restrict__ Zpart,
                                                    float* __restrict__ csPart) {
  const int bid = blockIdx.x;
  const int xcd = bid & 7, local = bid >> 3;
  const int bh = xcd * 4 + (local >> 5);
  const int s = (local >> 3) & 3;
  const int tqb = local & 7;
  const int b = bh >> 4, h = bh & 15;
  const int tid = threadIdx.x, lane = tid & 63, w = tid >> 6;
  const int l15 = lane & 15, l4 = lane >> 4;
  const size_t rs = 3072;

  __shared__ ushort ring[3][128 * 64];  // 48 KB

  const ushort* Qbase = QKV + (size_t)(b * 2048 + tqb * 256) * rs + h * 64;
  const ushort* Kbase = QKV + (size_t)(b * 2048 + s * 512) * rs + 1024 + h * 64;
  const float* zp = Zpart + bh * 2048 + s * 512;
  const int csl = ((tid & 7) ^ ((tid >> 3) & 7)) * 8;

#pragma unroll
  for (int i = 0; i < 8; i++) {
    int c = i * 256 + tid;
    GLD(Qbase + (size_t)(c >> 3) * rs + csl, (char*)ring[0] + c * 16);
  }
  const ushort* gk[4];
#pragma unroll
  for (int i = 0; i < 4; i++) {
    int c = i * 256 + tid;
    gk[i] = Kbase + (size_t)(c >> 3) * rs + csl;
    GLD(gk[i], (char*)ring[2] + c * 16);
  }
  asm volatile("s_waitcnt vmcnt(0)" ::: "memory");
  BARRIER();

  bf16x8 qf[4][2];
#pragma unroll
  for (int m = 0; m < 4; m++)
#pragma unroll
    for (int d = 0; d < 2; d++) {
      int r = w * 64 + m * 16 + l15;
      qf[m][d] =
          *(const bf16x8*)((const char*)ring[0] + r * 128 + (((d * 4 + l4) ^ (r & 7)) << 4));
    }
  asm volatile("s_waitcnt lgkmcnt(0)" ::: "memory");
  __builtin_amdgcn_sched_barrier(0);
  BARRIER();  // Q in regs; ring[0..1] free

#pragma unroll
  for (int i = 0; i < 4; i++) {
    int c = i * 256 + tid;
    GLD(gk[i] + 128 * rs, (char*)ring[0] + c * 16);  // K1
  }

  float cs[4][4] = {};
  const f32x4 zero4 = {0.f, 0.f, 0.f, 0.f};

  for (int t = 0; t < 4; ++t) {
    float rz[8];
#pragma unroll
    for (int n = 0; n < 8; n++) {
      int idx = t * 128 + n * 16 + l15;
      rz[n] = 1.0f / (zp[idx] + zp[65536 + idx] + zp[131072 + idx] + zp[196608 + idx]);
    }
    if (t < 2) {
      char* kd = (char*)ring[(t + 4) % 3];
#pragma unroll
      for (int i = 0; i < 4; i++) {
        int c = i * 256 + tid;
        GLD(gk[i] + (size_t)(t + 2) * 128 * rs, kd + c * 16);
      }
    }
    const char* kb = (const char*)ring[(t + 2) % 3];
#pragma unroll
    for (int half = 0; half < 2; ++half) {
      f32x4 acc[4][4];
      __builtin_amdgcn_s_setprio(1);
#pragma unroll
      for (int d = 0; d < 2; d++)
#pragma unroll
        for (int nn = 0; nn < 4; nn++) {
          int r = (half * 4 + nn) * 16 + l15;
          bf16x8 kft = *(const bf16x8*)(kb + r * 128 + (((d * 4 + l4) ^ (r & 7)) << 4));
#pragma unroll
          for (int m = 0; m < 4; m++)
            acc[m][nn] = __builtin_amdgcn_mfma_f32_16x16x32_bf16(
                qf[m][d], kft, d == 0 ? zero4 : acc[m][nn], 0, 0, 0);
        }
      __builtin_amdgcn_s_setprio(0);
#pragma unroll
      for (int m = 0; m < 4; m++)
#pragma unroll
        for (int nn = 0; nn < 4; nn++)
#pragma unroll
          for (int j = 0; j < 4; j++)
            cs[m][j] = fmaf(EXP2(acc[m][nn][j]), rz[half * 4 + nn], cs[m][j]);
    }
    if (t < 2) {
      asm volatile("s_waitcnt vmcnt(4)" ::: "memory");
      BARRIER();
    } else if (t == 2) {
      asm volatile("s_waitcnt vmcnt(0)" ::: "memory");
      BARRIER();
    }
  }

#pragma unroll
  for (int m = 0; m < 4; m++)
#pragma unroll
    for (int j = 0; j < 4; j++) {
      float v = cs[m][j];
      v += __shfl_xor(v, 1, 64);
      v += __shfl_xor(v, 2, 64);
      v += __shfl_xor(v, 4, 64);
      v += __shfl_xor(v, 8, 64);
      if (l15 == 0)
        csPart[(size_t)s * 65536 + bh * 2048 + tqb * 256 + w * 64 + m * 16 + l4 * 4 + j] = v;
    }
}

// ---------------- output GEMM: out = (V .* colsum) @ Wot + bo, fused ----------------
__global__ __launch_bounds__(256, 2) void k_gemm_out(const ushort* __restrict__ QKV,
                                                     const float* __restrict__ csPart,
                                                     const ushort* __restrict__ Wot,
                                                     float* __restrict__ out,
                                                     const float* __restrict__ bo) {
  __shared__ ushort As[2][128 * 64];  // 32 KB
  __shared__ ushort Bs[2][64 * 64];   // 16 KB
  const int tid = threadIdx.x;
  const int lane = tid & 63;
  const int wid = tid >> 6;
  const int wr = wid >> 1, wc = wid & 1;
  const int l15 = lane & 15, l4 = lane >> 4;

  const int L = blockIdx.x;
  const int f = (L & 7) * 64 + (L >> 3);
  const int row0 = (f & 31) * 128;
  const int col0 = (f >> 5) * 64;

  const int rt = tid >> 3, sl = tid & 7;
  int grow[4], gbh[4];
#pragma unroll
  for (int i = 0; i < 4; i++) {
    grow[i] = row0 + 32 * i + rt;
    gbh[i] = ((grow[i] >> 11) << 4) * 2048 + (grow[i] & 2047);  // b*16*2048 + tq
  }

  uint4 av[4];
  float csv[4];

#define ISSUE(t)                                                                   \
  do {                                                                             \
    _Pragma("unroll") for (int i = 0; i < 2; i++) {                                \
      int c = i * 256 + tid;                                                       \
      int rb = c >> 3;                                                             \
      GLD(Wot + (size_t)(col0 + rb) * 1024 + (t) * 64 + (((c & 7) ^ (rb & 7)) * 8),\
          (char*)Bs[(t) & 1] + c * 16);                                            \
    }                                                                              \
    _Pragma("unroll") for (int i = 0; i < 4; i++)                                  \
        av[i] = *(const uint4*)(QKV + (size_t)grow[i] * 3072 + 2048 + (t) * 64 +   \
                                sl * 8);                                           \
    _Pragma("unroll") for (int i = 0; i < 4; i++) {                                \
      int gg = gbh[i] + (t) * 2048;                                                \
      csv[i] = (csPart[gg] + csPart[65536 + gg]) +                                 \
               (csPart[131072 + gg] + csPart[196608 + gg]);                        \
    }                                                                              \
  } while (0)

#define WRITE_A(t)                                                                 \
  do {                                                                             \
    _Pragma("unroll") for (int i = 0; i < 4; i++) {                                \
      int r = 32 * i + rt;                                                         \
      const ushort* pv = (const ushort*)&av[i];                                    \
      ushort o[8];                                                                 \
      _Pragma("unroll") for (int k = 0; k < 8; k++)                                \
          o[k] = f2bf(bf2f(pv[k]) * csv[i]);                                       \
      *(uint4*)((char*)As[(t) & 1] + r * 128 + ((sl ^ (r & 7)) << 4)) =            \
          *(const uint4*)o;                                                        \
    }                                                                              \
  } while (0)

  int aoff[4][2], boff[2][2];
#pragma unroll
  for (int m = 0; m < 4; m++) {
    int r = wr * 64 + m * 16 + l15;
#pragma unroll
    for (int ks = 0; ks < 2; ks++)
      aoff[m][ks] = r * 128 + (((ks * 4 + l4) ^ (r & 7)) << 4);
  }
#pragma unroll
  for (int n = 0; n < 2; n++) {
    int r = wc * 32 + n * 16 + l15;
#pragma unroll
    for (int ks = 0; ks < 2; ks++)
      boff[n][ks] = r * 128 + (((ks * 4 + l4) ^ (r & 7)) << 4);
  }

  f32x4 acc[4][2] = {};

  ISSUE(0);
  asm volatile("s_waitcnt vmcnt(0)" ::: "memory");
  WRITE_A(0);
  asm volatile("s_waitcnt lgkmcnt(0)" ::: "memory");
  BARRIER();

  for (int t = 0; t < 16; ++t) {
    if (t < 15) ISSUE(t + 1);
    __builtin_amdgcn_sched_barrier(0);
    const char* Ab = (const char*)As[t & 1];
    const char* Bb = (const char*)Bs[t & 1];
    bf16x8 af[4][2], bf_[2][2];
#pragma unroll
    for (int m = 0; m < 4; m++)
#pragma unroll
      for (int ks = 0; ks < 2; ks++)
        af[m][ks] = *(const bf16x8*)(Ab + aoff[m][ks]);
#pragma unroll
    for (int n = 0; n < 2; n++)
#pragma unroll
      for (int ks = 0; ks < 2; ks++)
        bf_[n][ks] = *(const bf16x8*)(Bb + boff[n][ks]);
    __builtin_amdgcn_s_setprio(1);
#pragma unroll
    for (int m = 0; m < 4; m++)
#pragma unroll
      for (int n = 0; n < 2; n++)
#pragma unroll
        for (int ks = 0; ks < 2; ks++)
          acc[m][n] = __builtin_amdgcn_mfma_f32_16x16x32_bf16(af[m][ks], bf_[n][ks],
                                                              acc[m][n], 0, 0, 0);
    __builtin_amdgcn_s_setprio(0);
    if (t < 15) {
      asm volatile("s_waitcnt vmcnt(0)" ::: "memory");
      WRITE_A(t + 1);
      asm volatile("s_waitcnt lgkmcnt(0)" ::: "memory");
    }
    BARRIER();
  }

#undef ISSUE
#undef WRITE_A

#pragma unroll
  for (int m = 0; m < 4; m++)
#pragma unroll
    for (int n = 0; n < 2; n++) {
      int colg = col0 + wc * 32 + n * 16 + l15;
      float bias = bo[colg];
#pragma unroll
      for (int j = 0; j < 4; j++) {
        int rowg = row0 + wr * 64 + m * 16 + l4 * 4 + j;
        out[(size_t)rowg * 1024 + colg] = acc[m][n][j] + bias;
      }
    }
}

// ---------------- launch ----------------

extern "C" void kernel_launch(void* const* d_in, const int* in_sizes, int n_in,
                              void* d_out, int out_size, void* d_ws, size_t ws_size,
                              hipStream_t stream) {
  const float* x = (const float*)d_in[0];
  const float* Wq = (const float*)d_in[1];
  const float* bq = (const float*)d_in[2];
  const float* Wk = (const float*)d_in[3];
  const float* bk = (const float*)d_in[4];
  const float* Wv = (const float*)d_in[5];
  const float* bv = (const float*)d_in[6];
  const float* Wo = (const float*)d_in[7];
  const float* bo = (const float*)d_in[8];

  char* ws = (char*)d_ws;
  ushort* xb     = (ushort*)(ws);                  // 4096x1024 bf16   (8 MB)
  ushort* Wt     = (ushort*)(ws + 8388608);        // 3072x1024 bf16   (6 MB)
  ushort* Wot    = (ushort*)(ws + 14680064);       // 1024x1024 bf16   (2 MB)
  ushort* QKV    = (ushort*)(ws + 16777216);       // 4096x3072 bf16   (24 MB)
  float* Zpart   = (float*)(ws + 41943040);        // 4x32x2048 f32    (1 MB)
  float* csPart  = (float*)(ws + 43040768);        // 4x32x2048 f32    (1 MB)

  k_prep<<<dim3(32, 32, 5), dim3(32, 8), 0, stream>>>(x, Wq, Wk, Wv, Wo, xb, Wt, Wot);
  k_gemm_qkv<<<768, 256, 0, stream>>>(xb, Wt, QKV, bq, bk, bv);
  k_attn_z<<<1024, 256, 0, stream>>>(QKV, Zpart);
  k_attn_cs<<<1024, 256, 0, stream>>>(QKV, Zpart, csPart);
  k_gemm_out<<<512, 256, 0, stream>>>(QKV, csPart, Wot, (float*)d_out, bo);
}

// Round 13
// 121.228 us; speedup vs baseline: 2.1782x; 1.8036x over previous
//
#include <hip/hip_runtime.h>
#include <hip/hip_bf16.h>
#include <stdint.h>

typedef __attribute__((ext_vector_type(4))) float f32x4;
typedef __attribute__((ext_vector_type(8))) __bf16 bf16x8;

#define AS1 __attribute__((address_space(1)))
#define AS3 __attribute__((address_space(3)))

#if __has_builtin(__builtin_amdgcn_exp2f)
#define EXP2(x) __builtin_amdgcn_exp2f(x)
#else
#define EXP2(x) exp2f(x)
#endif

__device__ __forceinline__ ushort f2bf(float f) {
  uint32_t u = __builtin_bit_cast(uint32_t, f);
  u += 0x7fffu + ((u >> 16) & 1u);
  return (ushort)(u >> 16);
}
__device__ __forceinline__ float bf2f(ushort h) {
  uint32_t u = ((uint32_t)h) << 16;
  return __builtin_bit_cast(float, u);
}

#define SCK 0.18033688011112042f

#define GLD(src, dst) \
  __builtin_amdgcn_global_load_lds((const AS1 uint32_t*)(src), (AS3 uint32_t*)(dst), 16, 0, 0)

#define BARRIER()                          \
  do {                                     \
    __builtin_amdgcn_sched_barrier(0);     \
    __builtin_amdgcn_s_barrier();          \
    __builtin_amdgcn_sched_barrier(0);     \
  } while (0)

// ---------------- prep: weight transposes (z=0..3) + x f32->bf16 (z=4) ----------------

__global__ void k_prep(const float* __restrict__ x, const float* __restrict__ Wq,
                       const float* __restrict__ Wk, const float* __restrict__ Wv,
                       const float* __restrict__ Wo, ushort* __restrict__ xb,
                       ushort* __restrict__ Wt, ushort* __restrict__ Wot) {
  __shared__ float tile[32][33];
  int z = blockIdx.z;
  int tx = threadIdx.x, ty = threadIdx.y;  // (32,8)
  if (z == 4) {
    int base = (blockIdx.y * 32 + blockIdx.x) * 256 + ty * 32 + tx;
#pragma unroll
    for (int i = 0; i < 4; i++) {
      int idx = base + i * 262144;
      float4 v = ((const float4*)x)[idx];
      ushort4 o;
      o.x = f2bf(v.x); o.y = f2bf(v.y); o.z = f2bf(v.z); o.w = f2bf(v.w);
      ((ushort4*)xb)[idx] = o;
    }
    return;
  }
  const float* src = (z == 0) ? Wq : (z == 1) ? Wk : (z == 2) ? Wv : Wo;
  ushort* dst = (z < 3) ? (Wt + (size_t)z * 1048576) : Wot;
  float scale = (z == 1) ? SCK : 1.0f;
  int k0 = blockIdx.y * 32, n0 = blockIdx.x * 32;
#pragma unroll
  for (int i = 0; i < 4; i++)
    tile[ty + i * 8][tx] = src[(size_t)(k0 + ty + i * 8) * 1024 + n0 + tx];
  __syncthreads();
#pragma unroll
  for (int i = 0; i < 4; i++)
    dst[(size_t)(n0 + ty + i * 8) * 1024 + k0 + tx] = f2bf(tile[tx][ty + i * 8] * scale);
}

// ---------------- 128x128 BK=64 single-buffer GEMM, 3 blocks/CU (QKV) ----------------
__global__ __launch_bounds__(256, 3) void k_gemm_qkv(const ushort* __restrict__ A,
                                                     const ushort* __restrict__ Bt,
                                                     ushort* __restrict__ C,
                                                     const float* __restrict__ b0,
                                                     const float* __restrict__ b1,
                                                     const float* __restrict__ b2) {
  __shared__ ushort As[128 * 64];
  __shared__ ushort Bs[128 * 64];
  const int K = 1024, ldc = 3072;
  const int tid = threadIdx.x;
  const int lane = tid & 63;
  const int wid = tid >> 6;
  const int wr = wid >> 1, wc = wid & 1;
  const int l15 = lane & 15, l4 = lane >> 4;

  const int chunk = (int)gridDim.x >> 3;
  const int L = blockIdx.x;
  const int f = (L & 7) * chunk + (L >> 3);
  const int row0 = (f & 31) * 128;
  const int col0 = (f >> 5) * 128;
  const int T = K >> 6;

  const int rt = tid >> 3;
  const int cswz = ((tid & 7) ^ (rt & 7)) * 8;
  const ushort* Ap = A + (size_t)(row0 + rt) * K + cswz;
  const ushort* Bp = Bt + (size_t)(col0 + rt) * K + cswz;

  int aoff[4][2], boff[4][2];
#pragma unroll
  for (int m = 0; m < 4; m++) {
    int r = wr * 64 + m * 16 + l15;
#pragma unroll
    for (int ks = 0; ks < 2; ks++)
      aoff[m][ks] = r * 128 + (((ks * 4 + l4) ^ (r & 7)) << 4);
  }
#pragma unroll
  for (int n = 0; n < 4; n++) {
    int r = wc * 64 + n * 16 + l15;
#pragma unroll
    for (int ks = 0; ks < 2; ks++)
      boff[n][ks] = r * 128 + (((ks * 4 + l4) ^ (r & 7)) << 4);
  }

  f32x4 acc[4][4] = {};

  for (int t = 0; t < T; ++t) {
#pragma unroll
    for (int i = 0; i < 4; i++)
      GLD(Ap + (size_t)(32 * i) * K + t * 64, (char*)As + (i * 256 + tid) * 16);
#pragma unroll
    for (int i = 0; i < 4; i++)
      GLD(Bp + (size_t)(32 * i) * K + t * 64, (char*)Bs + (i * 256 + tid) * 16);
    asm volatile("s_waitcnt vmcnt(0)" ::: "memory");
    BARRIER();

    bf16x8 af[4][2], bf_[4][2];
#pragma unroll
    for (int m = 0; m < 4; m++)
#pragma unroll
      for (int ks = 0; ks < 2; ks++)
        af[m][ks] = *(const bf16x8*)((const char*)As + aoff[m][ks]);
#pragma unroll
    for (int n = 0; n < 4; n++)
#pragma unroll
      for (int ks = 0; ks < 2; ks++)
        bf_[n][ks] = *(const bf16x8*)((const char*)Bs + boff[n][ks]);

    __builtin_amdgcn_s_setprio(1);
#pragma unroll
    for (int m = 0; m < 4; m++)
#pragma unroll
      for (int n = 0; n < 4; n++)
#pragma unroll
        for (int ks = 0; ks < 2; ks++)
          acc[m][n] = __builtin_amdgcn_mfma_f32_16x16x32_bf16(af[m][ks], bf_[n][ks],
                                                              acc[m][n], 0, 0, 0);
    __builtin_amdgcn_s_setprio(0);
    BARRIER();
  }

#pragma unroll
  for (int m = 0; m < 4; m++)
#pragma unroll
    for (int n = 0; n < 4; n++) {
      int colg = col0 + wc * 64 + n * 16 + l15;
      float bias = (colg < 1024) ? b0[colg]
                                 : ((colg < 2048) ? b1[colg - 1024] * SCK : b2[colg - 2048]);
#pragma unroll
      for (int j = 0; j < 4; j++) {
        int rowg = row0 + wr * 64 + m * 16 + l4 * 4 + j;
        C[(size_t)rowg * ldc + colg] = f2bf(acc[m][n][j] + bias);
      }
    }
}

// ---------------- attention pass 1: Z[tk] = sum_tq exp2(S) ----------------
// r8 structure (80 KB LDS -> 2 blocks/CU, no VGPR clamp). Compute n-chunked
// into two acc[4][4] halves to cut peak register pressure.
__global__ __launch_bounds__(256, 2) void k_attn_z(const ushort* __restrict__ QKV,
                                                   float* __restrict__ Zpart) {
  const int bid = blockIdx.x;
  const int xcd = bid & 7, kk = bid >> 3;
  const int g = xcd * 8 + (kk >> 3);     // group 0..63 = (s,bh)
  const int tkb = kk & 7;
  const int bh = g & 31, s = g >> 5;
  const int b = bh >> 4, h = bh & 15;
  const int tid = threadIdx.x, lane = tid & 63, w = tid >> 6;
  const int l15 = lane & 15, l4 = lane >> 4;
  const size_t rs = 3072;

  __shared__ ushort Ks[256 * 64];      // 32 KB
  __shared__ ushort Qs[3][128 * 64];   // 48 KB

  const ushort* Kbase = QKV + (size_t)(b * 2048 + tkb * 256) * rs + 1024 + h * 64;
  const ushort* Qbase = QKV + (size_t)(b * 2048 + s * 1024) * rs + h * 64;

  const int csl = ((tid & 7) ^ ((tid >> 3) & 7)) * 8;

#pragma unroll
  for (int i = 0; i < 8; i++) {
    int c = i * 256 + tid;
    GLD(Kbase + (size_t)(c >> 3) * rs + csl, (char*)Ks + c * 16);
  }
  const ushort* gq[4];
#pragma unroll
  for (int i = 0; i < 4; i++) {
    int c = i * 256 + tid;
    gq[i] = Qbase + (size_t)(c >> 3) * rs + csl;
    GLD(gq[i], (char*)Qs[0] + c * 16);
  }
#pragma unroll
  for (int i = 0; i < 4; i++) {
    int c = i * 256 + tid;
    GLD(gq[i] + 128 * rs, (char*)Qs[1] + c * 16);
  }
  asm volatile("s_waitcnt vmcnt(4)" ::: "memory");  // K + Q0 resident
  BARRIER();

  bf16x8 kf[4][2];
#pragma unroll
  for (int m = 0; m < 4; m++)
#pragma unroll
    for (int d = 0; d < 2; d++) {
      int r = w * 64 + m * 16 + l15;
      kf[m][d] = *(const bf16x8*)((const char*)Ks + r * 128 + (((d * 4 + l4) ^ (r & 7)) << 4));
    }

  float z[4][4] = {};
  const f32x4 zero4 = {0.f, 0.f, 0.f, 0.f};

  for (int t = 0; t < 8; ++t) {
    if (t + 2 < 8) {
      char* qd = (char*)Qs[(t + 2) % 3];
#pragma unroll
      for (int i = 0; i < 4; i++) {
        int c = i * 256 + tid;
        GLD(gq[i] + (size_t)(t + 2) * 128 * rs, qd + c * 16);
      }
    }
    const char* qb = (const char*)Qs[t % 3];
#pragma unroll
    for (int half = 0; half < 2; ++half) {
      f32x4 acc[4][4];
      __builtin_amdgcn_s_setprio(1);
#pragma unroll
      for (int d = 0; d < 2; d++)
#pragma unroll
        for (int nn = 0; nn < 4; nn++) {
          int r = (half * 4 + nn) * 16 + l15;
          bf16x8 qf = *(const bf16x8*)(qb + r * 128 + (((d * 4 + l4) ^ (r & 7)) << 4));
#pragma unroll
          for (int m = 0; m < 4; m++)
            acc[m][nn] = __builtin_amdgcn_mfma_f32_16x16x32_bf16(
                kf[m][d], qf, d == 0 ? zero4 : acc[m][nn], 0, 0, 0);
        }
      __builtin_amdgcn_s_setprio(0);
#pragma unroll
      for (int m = 0; m < 4; m++)
#pragma unroll
        for (int nn = 0; nn < 4; nn++)
#pragma unroll
          for (int j = 0; j < 4; j++) z[m][j] += EXP2(acc[m][nn][j]);
    }
    if (t < 6) {
      asm volatile("s_waitcnt vmcnt(4)" ::: "memory");  // Q(t+1) resident
      BARRIER();
    } else if (t == 6) {
      asm volatile("s_waitcnt vmcnt(0)" ::: "memory");
      BARRIER();
    }
  }

#pragma unroll
  for (int m = 0; m < 4; m++)
#pragma unroll
    for (int j = 0; j < 4; j++) {
      float v = z[m][j];
      v += __shfl_xor(v, 1, 64);
      v += __shfl_xor(v, 2, 64);
      v += __shfl_xor(v, 4, 64);
      v += __shfl_xor(v, 8, 64);
      if (l15 == 0)
        Zpart[(size_t)s * 65536 + bh * 2048 + tkb * 256 + w * 64 + m * 16 + l4 * 4 + j] = v;
    }
}

// ---------------- attention pass 2: colsum[tq] = sum_tk exp2(S)/Z[tk] ----
__global__ __launch_bounds__(256, 2) void k_attn_cs(const ushort* __restrict__ QKV,
                                                    const float* __restrict__ Zpart,
                                                    float* __restrict__ csPart) {
  const int bid = blockIdx.x;
  const int xcd = bid & 7, kk = bid >> 3;
  const int g = xcd * 8 + (kk >> 3);
  const int tqb = kk & 7;
  const int bh = g & 31, s = g >> 5;
  const int b = bh >> 4, h = bh & 15;
  const int tid = threadIdx.x, lane = tid & 63, w = tid >> 6;
  const int l15 = lane & 15, l4 = lane >> 4;
  const size_t rs = 3072;

  __shared__ ushort Qs[256 * 64];
  __shared__ ushort Ks[3][128 * 64];

  const ushort* Qbase = QKV + (size_t)(b * 2048 + tqb * 256) * rs + h * 64;
  const ushort* Kbase = QKV + (size_t)(b * 2048 + s * 1024) * rs + 1024 + h * 64;
  const float* zp = Zpart + bh * 2048 + s * 1024;

  const int csl = ((tid & 7) ^ ((tid >> 3) & 7)) * 8;

#pragma unroll
  for (int i = 0; i < 8; i++) {
    int c = i * 256 + tid;
    GLD(Qbase + (size_t)(c >> 3) * rs + csl, (char*)Qs + c * 16);
  }
  const ushort* gk[4];
#pragma unroll
  for (int i = 0; i < 4; i++) {
    int c = i * 256 + tid;
    gk[i] = Kbase + (size_t)(c >> 3) * rs + csl;
    GLD(gk[i], (char*)Ks[0] + c * 16);
  }
#pragma unroll
  for (int i = 0; i < 4; i++) {
    int c = i * 256 + tid;
    GLD(gk[i] + 128 * rs, (char*)Ks[1] + c * 16);
  }
  asm volatile("s_waitcnt vmcnt(4)" ::: "memory");
  BARRIER();

  bf16x8 qf[4][2];
#pragma unroll
  for (int m = 0; m < 4; m++)
#pragma unroll
    for (int d = 0; d < 2; d++) {
      int r = w * 64 + m * 16 + l15;
      qf[m][d] = *(const bf16x8*)((const char*)Qs + r * 128 + (((d * 4 + l4) ^ (r & 7)) << 4));
    }

  float cs[4][4] = {};
  const f32x4 zero4 = {0.f, 0.f, 0.f, 0.f};

  for (int t = 0; t < 8; ++t) {
    // rz loads first (their wait leaves the K prefetch in flight)
    float rz[8];
#pragma unroll
    for (int n = 0; n < 8; n++) {
      int idx = t * 128 + n * 16 + l15;
      rz[n] = 1.0f / (zp[idx] + zp[65536 + idx]);
    }
    if (t + 2 < 8) {
      char* kd = (char*)Ks[(t + 2) % 3];
#pragma unroll
      for (int i = 0; i < 4; i++) {
        int c = i * 256 + tid;
        GLD(gk[i] + (size_t)(t + 2) * 128 * rs, kd + c * 16);
      }
    }
    const char* kb = (const char*)Ks[t % 3];
#pragma unroll
    for (int half = 0; half < 2; ++half) {
      f32x4 acc[4][4];
      __builtin_amdgcn_s_setprio(1);
#pragma unroll
      for (int d = 0; d < 2; d++)
#pragma unroll
        for (int nn = 0; nn < 4; nn++) {
          int r = (half * 4 + nn) * 16 + l15;
          bf16x8 kft = *(const bf16x8*)(kb + r * 128 + (((d * 4 + l4) ^ (r & 7)) << 4));
#pragma unroll
          for (int m = 0; m < 4; m++)
            acc[m][nn] = __builtin_amdgcn_mfma_f32_16x16x32_bf16(
                qf[m][d], kft, d == 0 ? zero4 : acc[m][nn], 0, 0, 0);
        }
      __builtin_amdgcn_s_setprio(0);
#pragma unroll
      for (int m = 0; m < 4; m++)
#pragma unroll
        for (int nn = 0; nn < 4; nn++)
#pragma unroll
          for (int j = 0; j < 4; j++)
            cs[m][j] = fmaf(EXP2(acc[m][nn][j]), rz[half * 4 + nn], cs[m][j]);
    }
    if (t < 6) {
      asm volatile("s_waitcnt vmcnt(4)" ::: "memory");
      BARRIER();
    } else if (t == 6) {
      asm volatile("s_waitcnt vmcnt(0)" ::: "memory");
      BARRIER();
    }
  }

#pragma unroll
  for (int m = 0; m < 4; m++)
#pragma unroll
    for (int j = 0; j < 4; j++) {
      float v = cs[m][j];
      v += __shfl_xor(v, 1, 64);
      v += __shfl_xor(v, 2, 64);
      v += __shfl_xor(v, 4, 64);
      v += __shfl_xor(v, 8, 64);
      if (l15 == 0)
        csPart[(size_t)s * 65536 + bh * 2048 + tqb * 256 + w * 64 + m * 16 + l4 * 4 + j] = v;
    }
}

// ---------------- output GEMM: out = (V .* colsum) @ Wot + bo, fused ----------------
__global__ __launch_bounds__(256, 2) void k_gemm_out(const ushort* __restrict__ QKV,
                                                     const float* __restrict__ csPart,
                                                     const ushort* __restrict__ Wot,
                                                     float* __restrict__ out,
                                                     const float* __restrict__ bo) {
  __shared__ ushort As[2][128 * 64];  // 32 KB
  __shared__ ushort Bs[2][64 * 64];   // 16 KB
  const int tid = threadIdx.x;
  const int lane = tid & 63;
  const int wid = tid >> 6;
  const int wr = wid >> 1, wc = wid & 1;
  const int l15 = lane & 15, l4 = lane >> 4;

  const int L = blockIdx.x;
  const int f = (L & 7) * 64 + (L >> 3);
  const int row0 = (f & 31) * 128;
  const int col0 = (f >> 5) * 64;

  const int rt = tid >> 3, sl = tid & 7;
  int grow[4], gbh[4];
#pragma unroll
  for (int i = 0; i < 4; i++) {
    grow[i] = row0 + 32 * i + rt;
    gbh[i] = ((grow[i] >> 11) << 4) * 2048 + (grow[i] & 2047);  // b*16*2048 + tq
  }

  uint4 av[4];
  float csv[4];

#define ISSUE(t)                                                                   \
  do {                                                                             \
    _Pragma("unroll") for (int i = 0; i < 2; i++) {                                \
      int c = i * 256 + tid;                                                       \
      int rb = c >> 3;                                                             \
      GLD(Wot + (size_t)(col0 + rb) * 1024 + (t) * 64 + (((c & 7) ^ (rb & 7)) * 8),\
          (char*)Bs[(t) & 1] + c * 16);                                            \
    }                                                                              \
    _Pragma("unroll") for (int i = 0; i < 4; i++)                                  \
        av[i] = *(const uint4*)(QKV + (size_t)grow[i] * 3072 + 2048 + (t) * 64 +   \
                                sl * 8);                                           \
    _Pragma("unroll") for (int i = 0; i < 4; i++) {                                \
      int gg = gbh[i] + (t) * 2048;                                                \
      csv[i] = csPart[gg] + csPart[65536 + gg];                                    \
    }                                                                              \
  } while (0)

#define WRITE_A(t)                                                                 \
  do {                                                                             \
    _Pragma("unroll") for (int i = 0; i < 4; i++) {                                \
      int r = 32 * i + rt;                                                         \
      const ushort* pv = (const ushort*)&av[i];                                    \
      ushort o[8];                                                                 \
      _Pragma("unroll") for (int k = 0; k < 8; k++)                                \
          o[k] = f2bf(bf2f(pv[k]) * csv[i]);                                       \
      *(uint4*)((char*)As[(t) & 1] + r * 128 + ((sl ^ (r & 7)) << 4)) =            \
          *(const uint4*)o;                                                        \
    }                                                                              \
  } while (0)

  int aoff[4][2], boff[2][2];
#pragma unroll
  for (int m = 0; m < 4; m++) {
    int r = wr * 64 + m * 16 + l15;
#pragma unroll
    for (int ks = 0; ks < 2; ks++)
      aoff[m][ks] = r * 128 + (((ks * 4 + l4) ^ (r & 7)) << 4);
  }
#pragma unroll
  for (int n = 0; n < 2; n++) {
    int r = wc * 32 + n * 16 + l15;
#pragma unroll
    for (int ks = 0; ks < 2; ks++)
      boff[n][ks] = r * 128 + (((ks * 4 + l4) ^ (r & 7)) << 4);
  }

  f32x4 acc[4][2] = {};

  ISSUE(0);
  asm volatile("s_waitcnt vmcnt(0)" ::: "memory");
  WRITE_A(0);
  asm volatile("s_waitcnt lgkmcnt(0)" ::: "memory");
  BARRIER();

  for (int t = 0; t < 16; ++t) {
    if (t < 15) ISSUE(t + 1);
    __builtin_amdgcn_sched_barrier(0);
    const char* Ab = (const char*)As[t & 1];
    const char* Bb = (const char*)Bs[t & 1];
    bf16x8 af[4][2], bf_[2][2];
#pragma unroll
    for (int m = 0; m < 4; m++)
#pragma unroll
      for (int ks = 0; ks < 2; ks++)
        af[m][ks] = *(const bf16x8*)(Ab + aoff[m][ks]);
#pragma unroll
    for (int n = 0; n < 2; n++)
#pragma unroll
      for (int ks = 0; ks < 2; ks++)
        bf_[n][ks] = *(const bf16x8*)(Bb + boff[n][ks]);
    __builtin_amdgcn_s_setprio(1);
#pragma unroll
    for (int m = 0; m < 4; m++)
#pragma unroll
      for (int n = 0; n < 2; n++)
#pragma unroll
        for (int ks = 0; ks < 2; ks++)
          acc[m][n] = __builtin_amdgcn_mfma_f32_16x16x32_bf16(af[m][ks], bf_[n][ks],
                                                              acc[m][n], 0, 0, 0);
    __builtin_amdgcn_s_setprio(0);
    if (t < 15) {
      asm volatile("s_waitcnt vmcnt(0)" ::: "memory");
      WRITE_A(t + 1);
      asm volatile("s_waitcnt lgkmcnt(0)" ::: "memory");
    }
    BARRIER();
  }

#undef ISSUE
#undef WRITE_A

#pragma unroll
  for (int m = 0; m < 4; m++)
#pragma unroll
    for (int n = 0; n < 2; n++) {
      int colg = col0 + wc * 32 + n * 16 + l15;
      float bias = bo[colg];
#pragma unroll
      for (int j = 0; j < 4; j++) {
        int rowg = row0 + wr * 64 + m * 16 + l4 * 4 + j;
        out[(size_t)rowg * 1024 + colg] = acc[m][n][j] + bias;
      }
    }
}

// ---------------- launch ----------------

extern "C" void kernel_launch(void* const* d_in, const int* in_sizes, int n_in,
                              void* d_out, int out_size, void* d_ws, size_t ws_size,
                              hipStream_t stream) {
  const float* x = (const float*)d_in[0];
  const float* Wq = (const float*)d_in[1];
  const float* bq = (const float*)d_in[2];
  const float* Wk = (const float*)d_in[3];
  const float* bk = (const float*)d_in[4];
  const float* Wv = (const float*)d_in[5];
  const float* bv = (const float*)d_in[6];
  const float* Wo = (const float*)d_in[7];
  const float* bo = (const float*)d_in[8];

  char* ws = (char*)d_ws;
  ushort* xb     = (ushort*)(ws);                  // 4096x1024 bf16   (8 MB)
  ushort* Wt     = (ushort*)(ws + 8388608);        // 3072x1024 bf16   (6 MB)
  ushort* Wot    = (ushort*)(ws + 14680064);       // 1024x1024 bf16   (2 MB)
  ushort* QKV    = (ushort*)(ws + 16777216);       // 4096x3072 bf16   (24 MB)
  float* Zpart   = (float*)(ws + 41943040);        // 2x32x2048 f32    (512 KB)
  float* csPart  = (float*)(ws + 42467328);        // 2x32x2048 f32    (512 KB)

  k_prep<<<dim3(32, 32, 5), dim3(32, 8), 0, stream>>>(x, Wq, Wk, Wv, Wo, xb, Wt, Wot);
  k_gemm_qkv<<<768, 256, 0, stream>>>(xb, Wt, QKV, bq, bk, bv);
  k_attn_z<<<512, 256, 0, stream>>>(QKV, Zpart);
  k_attn_cs<<<512, 256, 0, stream>>>(QKV, Zpart, csPart);
  k_gemm_out<<<512, 256, 0, stream>>>(QKV, csPart, Wot, (float*)d_out, bo);
}